// Round 14
// baseline (86.824 us; speedup 1.0000x reference)
//
#include <hip/hip_runtime.h>
#include <math.h>

#define BB 256
#define NN 1024
#define KK 64
#define EE 128
#define TM 64      // rows per block (4 waves x 16 rows)

typedef _Float16 half8 __attribute__((ext_vector_type(8)));
typedef __fp16 fp16x2 __attribute__((ext_vector_type(2)));
typedef float f32x4 __attribute__((ext_vector_type(4)));

// swizzled half-index for a [rows][128] f16 LDS tile: XOR 16B-slot bits by row&7
__device__ __forceinline__ int swz(int row, int halfcol) {
    return (row * EE + halfcol) ^ ((row & 7) << 3);
}

// async global->LDS 16B: linear LDS dest, per-lane global src
__device__ __forceinline__ void gload_lds16(const void* g, void* l) {
    __builtin_amdgcn_global_load_lds(
        (const __attribute__((address_space(1))) unsigned int*)g,
        (__attribute__((address_space(3))) unsigned int*)l, 16, 0, 0);
}

// ---------------- prep: Mt (f16), bias, t_abc (float4, revolution units); W2 -> f16 ----------------
// C = adj @ (w_real + i w_imag); M = [[Cr, Ci], [-Ci, Cr]]; x_pre = [cos|sin] @ M + [br|bi]
// Mt[f][j] = M[j][f]  (MFMA fragments = contiguous rows)
__global__ __launch_bounds__(256) void prep_kernel(
    const float* __restrict__ recip,
    const int* __restrict__ space_group,
    const float* __restrict__ abc,
    const float* __restrict__ graphs,
    const float* __restrict__ w_real,
    const float* __restrict__ w_imag,
    const float* __restrict__ b_real,
    const float* __restrict__ b_imag,
    const float* __restrict__ W2,
    _Float16* __restrict__ Mt,      // B*E*E
    float* __restrict__ bbout,      // B*E
    float* __restrict__ tabcP,      // B*K*4 (revolutions)
    _Float16* __restrict__ W2h)     // E*E
{
    const int b = blockIdx.x;
    const int t = threadIdx.x;
    const int sg = space_group[b] - 1;

    if (b < EE * EE / 256) {
        const int idx = b * 256 + t;
        W2h[idx] = (_Float16)W2[idx];
    }

    __shared__ float adjL[KK * KK];
    __shared__ float wrL[KK * KK];
    __shared__ float wiL[KK * KK];

    const float* adjG = graphs + (size_t)sg * KK * KK;
    const float* wrG  = w_real + (size_t)sg * KK * KK;
    const float* wiG  = w_imag + (size_t)sg * KK * KK;
    for (int idx = t; idx < KK * KK; idx += 256) {
        adjL[idx] = adjG[idx];
        wrL[idx]  = wrG[idx];
        wiL[idx]  = wiG[idx];
    }
    __syncthreads();

    const int i  = t >> 2;
    const int f0 = (t & 3) * 16;
    float cr[16], ci[16];
#pragma unroll
    for (int c = 0; c < 16; ++c) { cr[c] = 0.f; ci[c] = 0.f; }
    for (int k = 0; k < KK; ++k) {
        const float a = adjL[i * KK + k];
#pragma unroll
        for (int c = 0; c < 16; ++c) {
            cr[c] += a * wrL[k * KK + f0 + c];
            ci[c] += a * wiL[k * KK + f0 + c];
        }
    }
    _Float16* Mb = Mt + (size_t)b * EE * EE;
#pragma unroll
    for (int c = 0; c < 16; ++c) {
        const int f = f0 + c;
        Mb[f * EE + i]             = (_Float16)cr[c];
        Mb[f * EE + KK + i]        = (_Float16)(-ci[c]);
        Mb[(KK + f) * EE + i]      = (_Float16)ci[c];
        Mb[(KK + f) * EE + KK + i] = (_Float16)cr[c];
    }
    if (t < EE) {
        bbout[b * EE + t] = (t < KK) ? b_real[sg * KK + t] : b_imag[sg * KK + (t - KK)];
    }
    if (t < KK) {
        const float a0 = abc[t * 3 + 0], a1 = abc[t * 3 + 1], a2 = abc[t * 3 + 2];
        const float* R = recip + b * 9;
        float4 v;
        v.x = a0 * R[0] + a1 * R[1] + a2 * R[2];
        v.y = a0 * R[3] + a1 * R[4] + a2 * R[5];
        v.z = a0 * R[6] + a1 * R[7] + a2 * R[8];
        v.w = 0.f;
        *(float4*)&tabcP[((size_t)b * KK + t) * 4] = v;
    }
}

// ---------------- main fused MFMA kernel (both matmuls transposed; tree-LN epilogue) ----------------
__global__ __launch_bounds__(256) void main_kernel(
    const float* __restrict__ pos,      // B*N*3
    const _Float16* __restrict__ Mt,    // B*E*E f16
    const float* __restrict__ bball,    // B*E
    const float* __restrict__ tabcP,    // B*K*4 (revolutions)
    const _Float16* __restrict__ W2h,   // E*E f16
    const float* __restrict__ b2,       // E
    const float* __restrict__ gamma,    // E
    const float* __restrict__ beta,     // E
    float* __restrict__ out)            // B*N*E
{
    const int d = blockIdx.x;           // 0..4095
    // XCD swizzle: all 16 blocks of a batch on one XCD (Mt HBM-fetched once per batch)
    const int j  = d >> 3;              // 0..511 within XCD
    const int b  = (d & 7) * 32 + (j >> 4);
    const int n0 = (j & 15) * TM;
    const int t  = threadIdx.x;
    const int w    = t >> 6;            // wave 0..3 -> rows w*16..w*16+15
    const int lane = t & 63;
    const int ln15 = lane & 15;
    const int kg   = lane >> 4;         // 0..3

    __shared__ __align__(16) _Float16 Bt[EE * EE];  // 32KB: Mt, later W2
    __shared__ __align__(16) _Float16 X[TM * EE];   // 16KB: silu output

    // ---- issue async Mt staging: LDS linear, global source inverse-swizzled ----
    {
        const char* srcM = (const char*)(Mt + (size_t)b * EE * EE);
#pragma unroll
        for (int i = 0; i < 8; ++i) {
            const int c16 = t + i * 256;          // 0..2047
            const int row = c16 >> 4;
            const int sl  = c16 & 15;
            const int g   = row * 16 + (sl ^ (row & 7));
            gload_lds16(srcM + g * 16, (char*)Bt + c16 * 16);
        }
    }

    // ---- per-lane sincos fragments: HW sin/cos in revolutions (hides Mt load) ----
    // frag layout (A or B role): row/col = lane&15, k = (lane>>4)*8+j
    const int grow = n0 + w * 16 + ln15;
    const float* pr = pos + ((size_t)b * NN + grow) * 3;
    const float px = pr[0], py = pr[1], pz = pr[2];
    const float* tp = tabcP + (size_t)b * KK * 4;

    half8 afrag[4];
#pragma unroll
    for (int mq = 0; mq < 2; ++mq) {
        _Float16 cb[8], sb[8];
#pragma unroll
        for (int jj = 0; jj < 8; ++jj) {
            const int k = mq * 32 + kg * 8 + jj;
            const float4 tv = *(const float4*)&tp[k * 4];
            const float rev = px * tv.x + py * tv.y + pz * tv.z;  // phase / 2pi
            const float fr  = __builtin_amdgcn_fractf(rev);
            sb[jj] = (_Float16)__builtin_amdgcn_sinf(fr);   // sin(2pi*fr)
            cb[jj] = (_Float16)__builtin_amdgcn_cosf(fr);   // cos(2pi*fr)
        }
        afrag[mq]     = *(half8*)cb;   // cos -> k-chunks 0,1
        afrag[mq + 2] = *(half8*)sb;   // sin -> k-chunks 2,3
    }
    __syncthreads();   // drains vmcnt(0): Bt(Mt) ready

    // ---- matmul1 TRANSPOSED: D = Mt_tile (A-op) x sincos (B-op) ----
    // lane (ln15,kg) reg r2 holds X[row = w*16+ln15][col = nt*16 + kg*4 + r2]
    f32x4 acc[8];
#pragma unroll
    for (int nt = 0; nt < 8; ++nt) {
        const int n = nt * 16 + ln15;
        f32x4 a = {0.f, 0.f, 0.f, 0.f};
#pragma unroll
        for (int kc = 0; kc < 4; ++kc) {
            const half8 bf = *(const half8*)&Bt[swz(n, kc * 32 + kg * 8)];
            a = __builtin_amdgcn_mfma_f32_16x16x32_f16(bf, afrag[kc], a, 0, 0, 0);
        }
        acc[nt] = a;
    }
    __syncthreads();   // all waves done reading Bt(Mt) -> safe to overwrite

    // ---- issue async W2 staging NOW; silu below hides its L2 latency ----
    {
        const char* srcW = (const char*)W2h;
#pragma unroll
        for (int i = 0; i < 8; ++i) {
            const int c16 = t + i * 256;
            const int row = c16 >> 4;
            const int sl  = c16 & 15;
            const int g   = row * 16 + (sl ^ (row & 7));
            gload_lds16(srcW + g * 16, (char*)Bt + c16 * 16);
        }
    }

    // ---- bias + silu -> X: float4 bias, pkrtz pairs, ONE 8B write per nt ----
    {
        const int xrow = w * 16 + ln15;            // this lane's X row
        const float* bbp = bball + b * EE;
#pragma unroll
        for (int nt = 0; nt < 8; ++nt) {
            const int cb0 = nt * 16 + kg * 4;      // 4 consecutive cols
            const float4 bb4 = *(const float4*)&bbp[cb0];
            float sv[4];
            sv[0] = acc[nt][0] + bb4.x;
            sv[1] = acc[nt][1] + bb4.y;
            sv[2] = acc[nt][2] + bb4.z;
            sv[3] = acc[nt][3] + bb4.w;
#pragma unroll
            for (int r2 = 0; r2 < 4; ++r2)
                sv[r2] = sv[r2] * __builtin_amdgcn_rcpf(1.f + __expf(-sv[r2]));
            const fp16x2 p0 = __builtin_amdgcn_cvt_pkrtz(sv[0], sv[1]);
            const fp16x2 p1 = __builtin_amdgcn_cvt_pkrtz(sv[2], sv[3]);
            uint2 u;
            u.x = __builtin_bit_cast(unsigned int, p0);
            u.y = __builtin_bit_cast(unsigned int, p1);
            *(uint2*)&X[swz(xrow, cb0)] = u;       // 8B store; swizzle keeps 8B alignment
        }
    }

    // ---- X-frags for matmul2 from X (own wave's rows; in-wave LDS ordering) ----
    const int arow = w * 16 + ln15;
    half8 a2[4];
#pragma unroll
    for (int kc = 0; kc < 4; ++kc)
        a2[kc] = *(const half8*)&X[swz(arow, kc * 32 + kg * 8)];
    __syncthreads();   // drains vmcnt(0): Bt(W2) ready

    // ---- matmul2 TRANSPOSED: D2 = W2_tile (A-op) x X (B-op) = y^T ----
    // lane (ln15,kg) reg r2 holds y[row = w*16+ln15][feature = nt*16 + kg*4 + r2]
    f32x4 acc2[8];
#pragma unroll
    for (int nt = 0; nt < 8; ++nt) {
        const int n = nt * 16 + ln15;
        f32x4 a = {0.f, 0.f, 0.f, 0.f};
#pragma unroll
        for (int kc = 0; kc < 4; ++kc) {
            const half8 bf = *(const half8*)&Bt[swz(n, kc * 32 + kg * 8)];
            a = __builtin_amdgcn_mfma_f32_16x16x32_f16(bf, a2[kc], a, 0, 0, 0);
        }
        acc2[nt] = a;
    }

    // ---- + b2 (float4); LN partials: 8 INDEPENDENT per-nt chains, then 3-level tree ----
    float sp[8], qp[8];
#pragma unroll
    for (int nt = 0; nt < 8; ++nt) {
        const float4 b24 = *(const float4*)&b2[nt * 16 + kg * 4];
        const float v0 = acc2[nt][0] + b24.x;
        const float v1 = acc2[nt][1] + b24.y;
        const float v2 = acc2[nt][2] + b24.z;
        const float v3 = acc2[nt][3] + b24.w;
        acc2[nt][0] = v0; acc2[nt][1] = v1; acc2[nt][2] = v2; acc2[nt][3] = v3;
        sp[nt] = (v0 + v1) + (v2 + v3);
        qp[nt] = (v0 * v0 + v1 * v1) + (v2 * v2 + v3 * v3);
    }
    float s = ((sp[0] + sp[1]) + (sp[2] + sp[3])) + ((sp[4] + sp[5]) + (sp[6] + sp[7]));
    float q = ((qp[0] + qp[1]) + (qp[2] + qp[3])) + ((qp[4] + qp[5]) + (qp[6] + qp[7]));
    // reduce across the 4 kg lanes (lane bits 4 and 5); ln15 lanes hold distinct rows
    s += __shfl_xor(s, 16); q += __shfl_xor(q, 16);
    s += __shfl_xor(s, 32); q += __shfl_xor(q, 32);
    const float inv = 1.f / EE;
    const float mu = s * inv;
    const float rs = __builtin_amdgcn_rsqf(fmaxf(q * inv - mu * mu, 0.f) + 1e-5f);

    // ---- scale/shift (float4 gamma/beta), float4 stores: 8 x dwordx4 per lane ----
    float* orow = out + ((size_t)b * NN + n0 + w * 16 + ln15) * EE;
#pragma unroll
    for (int nt = 0; nt < 8; ++nt) {
        const int f0 = nt * 16 + kg * 4;
        const float4 g4  = *(const float4*)&gamma[f0];
        const float4 be4 = *(const float4*)&beta[f0];
        float4 o;
        o.x = (acc2[nt][0] - mu) * rs * g4.x + be4.x;
        o.y = (acc2[nt][1] - mu) * rs * g4.y + be4.y;
        o.z = (acc2[nt][2] - mu) * rs * g4.z + be4.z;
        o.w = (acc2[nt][3] - mu) * rs * g4.w + be4.w;
        *(float4*)&orow[f0] = o;
    }
}

extern "C" void kernel_launch(void* const* d_in, const int* in_sizes, int n_in,
                              void* d_out, int out_size, void* d_ws, size_t ws_size,
                              hipStream_t stream) {
    const float* pos    = (const float*)d_in[0];
    const float* recip  = (const float*)d_in[1];
    const int*   sgp    = (const int*)d_in[2];
    const float* abc    = (const float*)d_in[3];
    const float* graphs = (const float*)d_in[4];
    const float* wr     = (const float*)d_in[5];
    const float* wi     = (const float*)d_in[6];
    const float* br     = (const float*)d_in[7];
    const float* bi     = (const float*)d_in[8];
    const float* W2     = (const float*)d_in[9];
    const float* b2     = (const float*)d_in[10];
    const float* gm     = (const float*)d_in[11];
    const float* bt     = (const float*)d_in[12];
    float* out = (float*)d_out;

    char* ws = (char*)d_ws;
    _Float16* Mt    = (_Float16*)ws;                                     // 8 MiB
    char* p = ws + (size_t)BB * EE * EE * 2;
    _Float16* W2h   = (_Float16*)p;            p += EE * EE * 2;         // 32 KiB
    float*    bball = (float*)p;               p += (size_t)BB * EE * 4; // 128 KiB
    float*    tabcP = (float*)p;                                         // 256 KiB

    hipLaunchKernelGGL(prep_kernel, dim3(BB), dim3(256), 0, stream,
                       recip, sgp, abc, graphs, wr, wi, br, bi, W2, Mt, bball, tabcP, W2h);
    hipLaunchKernelGGL(main_kernel, dim3(BB * NN / TM), dim3(256), 0, stream,
                       pos, Mt, bball, tabcP, W2h, b2, gm, bt, out);
}

// Round 15
// 66.501 us; speedup vs baseline: 1.3056x; 1.3056x over previous
//
#include <hip/hip_runtime.h>
#include <math.h>

#define BB 256
#define NN 1024
#define KK 64
#define EE 128
#define TM 64      // rows per block (4 waves x 16 rows)

typedef _Float16 half8 __attribute__((ext_vector_type(8)));
typedef __fp16 fp16x2 __attribute__((ext_vector_type(2)));
typedef float f32x4 __attribute__((ext_vector_type(4)));

// swizzled half-index for a [rows][128] f16 LDS tile: XOR 16B-slot bits by row&7
__device__ __forceinline__ int swz(int row, int halfcol) {
    return (row * EE + halfcol) ^ ((row & 7) << 3);
}

// async global->LDS 16B: linear LDS dest, per-lane global src
__device__ __forceinline__ void gload_lds16(const void* g, void* l) {
    __builtin_amdgcn_global_load_lds(
        (const __attribute__((address_space(1))) unsigned int*)g,
        (__attribute__((address_space(3))) unsigned int*)l, 16, 0, 0);
}

// ---------------- prep: Mt (f16), bias, t_abc (float4, revolution units); W2 -> f16 ----------------
// C = adj @ (w_real + i w_imag); M = [[Cr, Ci], [-Ci, Cr]]; x_pre = [cos|sin] @ M + [br|bi]
// Mt[f][j] = M[j][f]  (MFMA fragments = contiguous rows)
__global__ __launch_bounds__(256) void prep_kernel(
    const float* __restrict__ recip,
    const int* __restrict__ space_group,
    const float* __restrict__ abc,
    const float* __restrict__ graphs,
    const float* __restrict__ w_real,
    const float* __restrict__ w_imag,
    const float* __restrict__ b_real,
    const float* __restrict__ b_imag,
    const float* __restrict__ W2,
    _Float16* __restrict__ Mt,      // B*E*E
    float* __restrict__ bbout,      // B*E
    float* __restrict__ tabcP,      // B*K*4 (revolutions)
    _Float16* __restrict__ W2h)     // E*E
{
    const int b = blockIdx.x;
    const int t = threadIdx.x;
    const int sg = space_group[b] - 1;

    if (b < EE * EE / 256) {
        const int idx = b * 256 + t;
        W2h[idx] = (_Float16)W2[idx];
    }

    __shared__ float adjL[KK * KK];
    __shared__ float wrL[KK * KK];
    __shared__ float wiL[KK * KK];

    const float* adjG = graphs + (size_t)sg * KK * KK;
    const float* wrG  = w_real + (size_t)sg * KK * KK;
    const float* wiG  = w_imag + (size_t)sg * KK * KK;
    for (int idx = t; idx < KK * KK; idx += 256) {
        adjL[idx] = adjG[idx];
        wrL[idx]  = wrG[idx];
        wiL[idx]  = wiG[idx];
    }
    __syncthreads();

    const int i  = t >> 2;
    const int f0 = (t & 3) * 16;
    float cr[16], ci[16];
#pragma unroll
    for (int c = 0; c < 16; ++c) { cr[c] = 0.f; ci[c] = 0.f; }
    for (int k = 0; k < KK; ++k) {
        const float a = adjL[i * KK + k];
#pragma unroll
        for (int c = 0; c < 16; ++c) {
            cr[c] += a * wrL[k * KK + f0 + c];
            ci[c] += a * wiL[k * KK + f0 + c];
        }
    }
    _Float16* Mb = Mt + (size_t)b * EE * EE;
#pragma unroll
    for (int c = 0; c < 16; ++c) {
        const int f = f0 + c;
        Mb[f * EE + i]             = (_Float16)cr[c];
        Mb[f * EE + KK + i]        = (_Float16)(-ci[c]);
        Mb[(KK + f) * EE + i]      = (_Float16)ci[c];
        Mb[(KK + f) * EE + KK + i] = (_Float16)cr[c];
    }
    if (t < EE) {
        bbout[b * EE + t] = (t < KK) ? b_real[sg * KK + t] : b_imag[sg * KK + (t - KK)];
    }
    if (t < KK) {
        const float a0 = abc[t * 3 + 0], a1 = abc[t * 3 + 1], a2 = abc[t * 3 + 2];
        const float* R = recip + b * 9;
        float4 v;
        v.x = a0 * R[0] + a1 * R[1] + a2 * R[2];
        v.y = a0 * R[3] + a1 * R[4] + a2 * R[5];
        v.z = a0 * R[6] + a1 * R[7] + a2 * R[8];
        v.w = 0.f;
        *(float4*)&tabcP[((size_t)b * KK + t) * 4] = v;
    }
}

// ---------------- main fused MFMA kernel (R12 structure + setprio around MFMA) ----------------
__global__ __launch_bounds__(256) void main_kernel(
    const float* __restrict__ pos,      // B*N*3
    const _Float16* __restrict__ Mt,    // B*E*E f16
    const float* __restrict__ bball,    // B*E
    const float* __restrict__ tabcP,    // B*K*4 (revolutions)
    const _Float16* __restrict__ W2h,   // E*E f16
    const float* __restrict__ b2,       // E
    const float* __restrict__ gamma,    // E
    const float* __restrict__ beta,     // E
    float* __restrict__ out)            // B*N*E
{
    const int d = blockIdx.x;           // 0..4095
    // XCD swizzle: all 16 blocks of a batch on one XCD (Mt HBM-fetched once per batch)
    const int j  = d >> 3;              // 0..511 within XCD
    const int b  = (d & 7) * 32 + (j >> 4);
    const int n0 = (j & 15) * TM;
    const int t  = threadIdx.x;
    const int w    = t >> 6;            // wave 0..3 -> rows w*16..w*16+15
    const int lane = t & 63;
    const int ln15 = lane & 15;
    const int kg   = lane >> 4;         // 0..3

    __shared__ __align__(16) _Float16 Bt[EE * EE];  // 32KB: Mt, later W2
    __shared__ __align__(16) _Float16 X[TM * EE];   // 16KB: silu output

    // ---- issue async Mt staging: LDS linear, global source inverse-swizzled ----
    {
        const char* srcM = (const char*)(Mt + (size_t)b * EE * EE);
#pragma unroll
        for (int i = 0; i < 8; ++i) {
            const int c16 = t + i * 256;          // 0..2047
            const int row = c16 >> 4;
            const int sl  = c16 & 15;
            const int g   = row * 16 + (sl ^ (row & 7));
            gload_lds16(srcM + g * 16, (char*)Bt + c16 * 16);
        }
    }

    // ---- per-lane sincos fragments: HW sin/cos in revolutions (hides Mt load) ----
    // frag layout (A or B role): row/col = lane&15, k = (lane>>4)*8+j
    const int grow = n0 + w * 16 + ln15;
    const float* pr = pos + ((size_t)b * NN + grow) * 3;
    const float px = pr[0], py = pr[1], pz = pr[2];
    const float* tp = tabcP + (size_t)b * KK * 4;

    half8 afrag[4];
#pragma unroll
    for (int mq = 0; mq < 2; ++mq) {
        _Float16 cb[8], sb[8];
#pragma unroll
        for (int jj = 0; jj < 8; ++jj) {
            const int k = mq * 32 + kg * 8 + jj;
            const float4 tv = *(const float4*)&tp[k * 4];
            const float rev = px * tv.x + py * tv.y + pz * tv.z;  // phase / 2pi
            const float fr  = __builtin_amdgcn_fractf(rev);
            sb[jj] = (_Float16)__builtin_amdgcn_sinf(fr);   // sin(2pi*fr)
            cb[jj] = (_Float16)__builtin_amdgcn_cosf(fr);   // cos(2pi*fr)
        }
        afrag[mq]     = *(half8*)cb;   // cos -> k-chunks 0,1
        afrag[mq + 2] = *(half8*)sb;   // sin -> k-chunks 2,3
    }
    __syncthreads();   // drains vmcnt(0): Bt(Mt) ready

    // ---- matmul1 TRANSPOSED: D = Mt_tile (A-op) x sincos (B-op) ----
    // lane (ln15,kg) reg r2 holds X[row = w*16+ln15][col = nt*16 + kg*4 + r2]
    __builtin_amdgcn_s_setprio(1);
    f32x4 acc[8];
#pragma unroll
    for (int nt = 0; nt < 8; ++nt) {
        const int n = nt * 16 + ln15;
        f32x4 a = {0.f, 0.f, 0.f, 0.f};
#pragma unroll
        for (int kc = 0; kc < 4; ++kc) {
            const half8 bf = *(const half8*)&Bt[swz(n, kc * 32 + kg * 8)];
            a = __builtin_amdgcn_mfma_f32_16x16x32_f16(bf, afrag[kc], a, 0, 0, 0);
        }
        acc[nt] = a;
    }
    __builtin_amdgcn_s_setprio(0);
    __syncthreads();   // all waves done reading Bt(Mt) -> safe to overwrite

    // ---- issue async W2 staging NOW; silu below hides its L2 latency ----
    {
        const char* srcW = (const char*)W2h;
#pragma unroll
        for (int i = 0; i < 8; ++i) {
            const int c16 = t + i * 256;
            const int row = c16 >> 4;
            const int sl  = c16 & 15;
            const int g   = row * 16 + (sl ^ (row & 7));
            gload_lds16(srcW + g * 16, (char*)Bt + c16 * 16);
        }
    }

    // ---- bias + silu -> X: float4 bias, pkrtz pairs, ONE 8B write per nt ----
    {
        const int xrow = w * 16 + ln15;            // this lane's X row
        const float* bbp = bball + b * EE;
#pragma unroll
        for (int nt = 0; nt < 8; ++nt) {
            const int cb0 = nt * 16 + kg * 4;      // 4 consecutive cols
            const float4 bb4 = *(const float4*)&bbp[cb0];
            float sv[4];
            sv[0] = acc[nt][0] + bb4.x;
            sv[1] = acc[nt][1] + bb4.y;
            sv[2] = acc[nt][2] + bb4.z;
            sv[3] = acc[nt][3] + bb4.w;
#pragma unroll
            for (int r2 = 0; r2 < 4; ++r2)
                sv[r2] = sv[r2] * __builtin_amdgcn_rcpf(1.f + __expf(-sv[r2]));
            const fp16x2 p0 = __builtin_amdgcn_cvt_pkrtz(sv[0], sv[1]);
            const fp16x2 p1 = __builtin_amdgcn_cvt_pkrtz(sv[2], sv[3]);
            uint2 u;
            u.x = __builtin_bit_cast(unsigned int, p0);
            u.y = __builtin_bit_cast(unsigned int, p1);
            *(uint2*)&X[swz(xrow, cb0)] = u;       // 8B store; swizzle keeps 8B alignment
        }
    }

    // ---- X-frags for matmul2 from X (own wave's rows; in-wave LDS ordering) ----
    const int arow = w * 16 + ln15;
    half8 a2[4];
#pragma unroll
    for (int kc = 0; kc < 4; ++kc)
        a2[kc] = *(const half8*)&X[swz(arow, kc * 32 + kg * 8)];
    __syncthreads();   // drains vmcnt(0): Bt(W2) ready

    // ---- matmul2: y = X @ W2^T (normal orientation; D rows = n) ----
    __builtin_amdgcn_s_setprio(1);
    f32x4 acc2[8];
#pragma unroll
    for (int nt = 0; nt < 8; ++nt) {
        const int n = nt * 16 + ln15;
        f32x4 a = {0.f, 0.f, 0.f, 0.f};
#pragma unroll
        for (int kc = 0; kc < 4; ++kc) {
            const half8 bf = *(const half8*)&Bt[swz(n, kc * 32 + kg * 8)];
            a = __builtin_amdgcn_mfma_f32_16x16x32_f16(a2[kc], bf, a, 0, 0, 0);
        }
        acc2[nt] = a;
    }
    __builtin_amdgcn_s_setprio(0);

    // ---- + b2, LayerNorm over E (16-lane shfl, v_rsq), store ----
    float s[4] = {0.f, 0.f, 0.f, 0.f}, q[4] = {0.f, 0.f, 0.f, 0.f};
#pragma unroll
    for (int nt = 0; nt < 8; ++nt) {
        const int col = nt * 16 + ln15;
        const float b2v = b2[col];
#pragma unroll
        for (int r2 = 0; r2 < 4; ++r2) {
            const float v = acc2[nt][r2] + b2v;
            acc2[nt][r2] = v;
            s[r2] += v;
            q[r2] += v * v;
        }
    }
#pragma unroll
    for (int m = 1; m < 16; m <<= 1) {
#pragma unroll
        for (int r2 = 0; r2 < 4; ++r2) {
            s[r2] += __shfl_xor(s[r2], m);
            q[r2] += __shfl_xor(q[r2], m);
        }
    }
    const float inv = 1.f / EE;
    float mu[4], rs[4];
#pragma unroll
    for (int r2 = 0; r2 < 4; ++r2) {
        mu[r2] = s[r2] * inv;
        rs[r2] = __builtin_amdgcn_rsqf(fmaxf(q[r2] * inv - mu[r2] * mu[r2], 0.f) + 1e-5f);
    }
#pragma unroll
    for (int nt = 0; nt < 8; ++nt) {
        const int col = nt * 16 + ln15;
        const float g  = gamma[col];
        const float be = beta[col];
#pragma unroll
        for (int r2 = 0; r2 < 4; ++r2) {
            const int rr = w * 16 + kg * 4 + r2;
            out[((size_t)b * NN + n0 + rr) * EE + col] =
                (acc2[nt][r2] - mu[r2]) * rs[r2] * g + be;
        }
    }
}

extern "C" void kernel_launch(void* const* d_in, const int* in_sizes, int n_in,
                              void* d_out, int out_size, void* d_ws, size_t ws_size,
                              hipStream_t stream) {
    const float* pos    = (const float*)d_in[0];
    const float* recip  = (const float*)d_in[1];
    const int*   sgp    = (const int*)d_in[2];
    const float* abc    = (const float*)d_in[3];
    const float* graphs = (const float*)d_in[4];
    const float* wr     = (const float*)d_in[5];
    const float* wi     = (const float*)d_in[6];
    const float* br     = (const float*)d_in[7];
    const float* bi     = (const float*)d_in[8];
    const float* W2     = (const float*)d_in[9];
    const float* b2     = (const float*)d_in[10];
    const float* gm     = (const float*)d_in[11];
    const float* bt     = (const float*)d_in[12];
    float* out = (float*)d_out;

    char* ws = (char*)d_ws;
    _Float16* Mt    = (_Float16*)ws;                                     // 8 MiB
    char* p = ws + (size_t)BB * EE * EE * 2;
    _Float16* W2h   = (_Float16*)p;            p += EE * EE * 2;         // 32 KiB
    float*    bball = (float*)p;               p += (size_t)BB * EE * 4; // 128 KiB
    float*    tabcP = (float*)p;                                         // 256 KiB

    hipLaunchKernelGGL(prep_kernel, dim3(BB), dim3(256), 0, stream,
                       recip, sgp, abc, graphs, wr, wi, br, bi, W2, Mt, bball, tabcP, W2h);
    hipLaunchKernelGGL(main_kernel, dim3(BB * NN / TM), dim3(256), 0, stream,
                       pos, Mt, bball, tabcP, W2h, b2, gm, bt, out);
}

// Round 16
// 62.800 us; speedup vs baseline: 1.3825x; 1.0589x over previous
//
#include <hip/hip_runtime.h>
#include <math.h>

#define BB 256
#define NN 1024
#define KK 64
#define EE 128
#define TM 64      // rows per block (4 waves x 16 rows)

typedef _Float16 half8 __attribute__((ext_vector_type(8)));
typedef __fp16 fp16x2 __attribute__((ext_vector_type(2)));
typedef float f32x4 __attribute__((ext_vector_type(4)));

// swizzled half-index for a [rows][128] f16 LDS tile: XOR 16B-slot bits by row&7
__device__ __forceinline__ int swz(int row, int halfcol) {
    return (row * EE + halfcol) ^ ((row & 7) << 3);
}
// swizzled half-index for a compact [128][64] f16 LDS tile (W2 k-half)
__device__ __forceinline__ int swz64(int row, int halfcol) {
    return (row << 6) + (halfcol ^ ((row & 7) << 3));
}

// async global->LDS 16B: linear LDS dest, per-lane global src
__device__ __forceinline__ void gload_lds16(const void* g, void* l) {
    __builtin_amdgcn_global_load_lds(
        (const __attribute__((address_space(1))) unsigned int*)g,
        (__attribute__((address_space(3))) unsigned int*)l, 16, 0, 0);
}

// ---------------- prep: Mt (f16), bias, t_abc (float4, revolution units); W2 -> f16 ----------------
// C = adj @ (w_real + i w_imag); M = [[Cr, Ci], [-Ci, Cr]]; x_pre = [cos|sin] @ M + [br|bi]
// Mt[f][j] = M[j][f]  (MFMA fragments = contiguous rows)
__global__ __launch_bounds__(256) void prep_kernel(
    const float* __restrict__ recip,
    const int* __restrict__ space_group,
    const float* __restrict__ abc,
    const float* __restrict__ graphs,
    const float* __restrict__ w_real,
    const float* __restrict__ w_imag,
    const float* __restrict__ b_real,
    const float* __restrict__ b_imag,
    const float* __restrict__ W2,
    _Float16* __restrict__ Mt,      // B*E*E
    float* __restrict__ bbout,      // B*E
    float* __restrict__ tabcP,      // B*K*4 (revolutions)
    _Float16* __restrict__ W2h)     // E*E
{
    const int b = blockIdx.x;
    const int t = threadIdx.x;
    const int sg = space_group[b] - 1;

    if (b < EE * EE / 256) {
        const int idx = b * 256 + t;
        W2h[idx] = (_Float16)W2[idx];
    }

    __shared__ float adjL[KK * KK];
    __shared__ float wrL[KK * KK];
    __shared__ float wiL[KK * KK];

    const float* adjG = graphs + (size_t)sg * KK * KK;
    const float* wrG  = w_real + (size_t)sg * KK * KK;
    const float* wiG  = w_imag + (size_t)sg * KK * KK;
    for (int idx = t; idx < KK * KK; idx += 256) {
        adjL[idx] = adjG[idx];
        wrL[idx]  = wrG[idx];
        wiL[idx]  = wiG[idx];
    }
    __syncthreads();

    const int i  = t >> 2;
    const int f0 = (t & 3) * 16;
    float cr[16], ci[16];
#pragma unroll
    for (int c = 0; c < 16; ++c) { cr[c] = 0.f; ci[c] = 0.f; }
    for (int k = 0; k < KK; ++k) {
        const float a = adjL[i * KK + k];
#pragma unroll
        for (int c = 0; c < 16; ++c) {
            cr[c] += a * wrL[k * KK + f0 + c];
            ci[c] += a * wiL[k * KK + f0 + c];
        }
    }
    _Float16* Mb = Mt + (size_t)b * EE * EE;
#pragma unroll
    for (int c = 0; c < 16; ++c) {
        const int f = f0 + c;
        Mb[f * EE + i]             = (_Float16)cr[c];
        Mb[f * EE + KK + i]        = (_Float16)(-ci[c]);
        Mb[(KK + f) * EE + i]      = (_Float16)ci[c];
        Mb[(KK + f) * EE + KK + i] = (_Float16)cr[c];
    }
    if (t < EE) {
        bbout[b * EE + t] = (t < KK) ? b_real[sg * KK + t] : b_imag[sg * KK + (t - KK)];
    }
    if (t < KK) {
        const float a0 = abc[t * 3 + 0], a1 = abc[t * 3 + 1], a2 = abc[t * 3 + 2];
        const float* R = recip + b * 9;
        float4 v;
        v.x = a0 * R[0] + a1 * R[1] + a2 * R[2];
        v.y = a0 * R[3] + a1 * R[4] + a2 * R[5];
        v.z = a0 * R[6] + a1 * R[7] + a2 * R[8];
        v.w = 0.f;
        *(float4*)&tabcP[((size_t)b * KK + t) * 4] = v;
    }
}

// ---------------- main fused MFMA kernel: 32KB LDS -> 4 blocks/CU (16 waves) ----------------
// Bt (32KB) lifecycle: [full Mt] -> mm1 -> [W2 k-half in 0:16K | X in 16K:32K] -> mm2(kc01)
//                      -> [W2 k-half-1 overwrites 0:16K] -> mm2(kc23)
__global__ __launch_bounds__(256, 4) void main_kernel(
    const float* __restrict__ pos,      // B*N*3
    const _Float16* __restrict__ Mt,    // B*E*E f16
    const float* __restrict__ bball,    // B*E
    const float* __restrict__ tabcP,    // B*K*4 (revolutions)
    const _Float16* __restrict__ W2h,   // E*E f16
    const float* __restrict__ b2,       // E
    const float* __restrict__ gamma,    // E
    const float* __restrict__ beta,     // E
    float* __restrict__ out)            // B*N*E
{
    const int d = blockIdx.x;           // 0..4095
    // XCD swizzle: all 16 blocks of a batch on one XCD (Mt HBM-fetched once per batch)
    const int j  = d >> 3;              // 0..511 within XCD
    const int b  = (d & 7) * 32 + (j >> 4);
    const int n0 = (j & 15) * TM;
    const int t  = threadIdx.x;
    const int w    = t >> 6;            // wave 0..3 -> rows w*16..w*16+15
    const int lane = t & 63;
    const int ln15 = lane & 15;
    const int kg   = lane >> 4;         // 0..3

    __shared__ __align__(16) _Float16 Bt[EE * EE];  // 32KB EXACTLY (4 blocks/CU)
    _Float16* X = Bt + (EE * EE) / 2;               // upper 16KB after Mt is dead

    // ---- issue async Mt staging: LDS linear, global source inverse-swizzled ----
    {
        const char* srcM = (const char*)(Mt + (size_t)b * EE * EE);
#pragma unroll
        for (int i = 0; i < 8; ++i) {
            const int c16 = t + i * 256;          // 0..2047
            const int row = c16 >> 4;
            const int sl  = c16 & 15;
            const int g   = row * 16 + (sl ^ (row & 7));
            gload_lds16(srcM + g * 16, (char*)Bt + c16 * 16);
        }
    }

    // ---- per-lane sincos fragments: HW sin/cos in revolutions (hides Mt load) ----
    const int grow = n0 + w * 16 + ln15;
    const float* pr = pos + ((size_t)b * NN + grow) * 3;
    const float px = pr[0], py = pr[1], pz = pr[2];
    const float* tp = tabcP + (size_t)b * KK * 4;

    half8 afrag[4];
#pragma unroll
    for (int mq = 0; mq < 2; ++mq) {
        _Float16 cb[8], sb[8];
#pragma unroll
        for (int jj = 0; jj < 8; ++jj) {
            const int k = mq * 32 + kg * 8 + jj;
            const float4 tv = *(const float4*)&tp[k * 4];
            const float rev = px * tv.x + py * tv.y + pz * tv.z;  // phase / 2pi
            const float fr  = __builtin_amdgcn_fractf(rev);
            sb[jj] = (_Float16)__builtin_amdgcn_sinf(fr);
            cb[jj] = (_Float16)__builtin_amdgcn_cosf(fr);
        }
        afrag[mq]     = *(half8*)cb;   // cos -> k-chunks 0,1
        afrag[mq + 2] = *(half8*)sb;   // sin -> k-chunks 2,3
    }
    __syncthreads();   // bar1: Bt(Mt) ready

    // ---- matmul1 TRANSPOSED: lane holds X[row=w*16+ln15][col=nt*16+kg*4+r2] ----
    __builtin_amdgcn_s_setprio(1);
    f32x4 acc[8];
#pragma unroll
    for (int nt = 0; nt < 8; ++nt) {
        const int n = nt * 16 + ln15;
        f32x4 a = {0.f, 0.f, 0.f, 0.f};
#pragma unroll
        for (int kc = 0; kc < 4; ++kc) {
            const half8 bf = *(const half8*)&Bt[swz(n, kc * 32 + kg * 8)];
            a = __builtin_amdgcn_mfma_f32_16x16x32_f16(bf, afrag[kc], a, 0, 0, 0);
        }
        acc[nt] = a;
    }
    __builtin_amdgcn_s_setprio(0);
    __syncthreads();   // bar2: Mt dead -> Bt reusable

    // ---- issue async W2 k-half-0 staging (compact [128][64] into Bt[0:16K)) ----
    {
        const char* srcW = (const char*)W2h;
#pragma unroll
        for (int i = 0; i < 4; ++i) {
            const int c = t + i * 256;            // 0..1023
            const int n = c >> 3;
            const int s = c & 7;
            const int g = n * 16 + (s ^ (n & 7)); // source slots 0..7 (k 0..63)
            gload_lds16(srcW + g * 16, (char*)Bt + c * 16);
        }
    }

    // ---- bias + silu -> X (upper 16K): float4 bias, pkrtz, one 8B write per nt ----
    {
        const int xrow = w * 16 + ln15;
        const float* bbp = bball + b * EE;
#pragma unroll
        for (int nt = 0; nt < 8; ++nt) {
            const int cb0 = nt * 16 + kg * 4;
            const float4 bb4 = *(const float4*)&bbp[cb0];
            float sv[4];
            sv[0] = acc[nt][0] + bb4.x;
            sv[1] = acc[nt][1] + bb4.y;
            sv[2] = acc[nt][2] + bb4.z;
            sv[3] = acc[nt][3] + bb4.w;
#pragma unroll
            for (int r2 = 0; r2 < 4; ++r2)
                sv[r2] = sv[r2] * __builtin_amdgcn_rcpf(1.f + __expf(-sv[r2]));
            const fp16x2 p0 = __builtin_amdgcn_cvt_pkrtz(sv[0], sv[1]);
            const fp16x2 p1 = __builtin_amdgcn_cvt_pkrtz(sv[2], sv[3]);
            uint2 u;
            u.x = __builtin_bit_cast(unsigned int, p0);
            u.y = __builtin_bit_cast(unsigned int, p1);
            *(uint2*)&X[swz(xrow, cb0)] = u;
        }
    }

    // ---- X-frags for matmul2 (own wave's rows; in-wave LDS ordering) ----
    const int arow = w * 16 + ln15;
    half8 a2[4];
#pragma unroll
    for (int kc = 0; kc < 4; ++kc)
        a2[kc] = *(const half8*)&X[swz(arow, kc * 32 + kg * 8)];
    __syncthreads();   // bar3: W2 half-0 ready

    // ---- matmul2 part 1: kc = 0,1 from compact half-0 ----
    __builtin_amdgcn_s_setprio(1);
    f32x4 acc2[8];
#pragma unroll
    for (int nt = 0; nt < 8; ++nt) {
        const int n = nt * 16 + ln15;
        f32x4 a = {0.f, 0.f, 0.f, 0.f};
#pragma unroll
        for (int kc = 0; kc < 2; ++kc) {
            const half8 bf = *(const half8*)&Bt[swz64(n, kc * 32 + kg * 8)];
            a = __builtin_amdgcn_mfma_f32_16x16x32_f16(a2[kc], bf, a, 0, 0, 0);
        }
        acc2[nt] = a;
    }
    __builtin_amdgcn_s_setprio(0);
    __syncthreads();   // bar4: half-0 dead

    // ---- issue async W2 k-half-1 staging (overwrites Bt[0:16K)) ----
    {
        const char* srcW = (const char*)W2h;
#pragma unroll
        for (int i = 0; i < 4; ++i) {
            const int c = t + i * 256;
            const int n = c >> 3;
            const int s = c & 7;
            const int g = n * 16 + 8 + (s ^ (n & 7));  // source slots 8..15 (k 64..127)
            gload_lds16(srcW + g * 16, (char*)Bt + c * 16);
        }
    }
    __syncthreads();   // bar5: half-1 ready

    // ---- matmul2 part 2: kc = 2,3 ----
    __builtin_amdgcn_s_setprio(1);
#pragma unroll
    for (int nt = 0; nt < 8; ++nt) {
        const int n = nt * 16 + ln15;
        f32x4 a = acc2[nt];
#pragma unroll
        for (int kc = 0; kc < 2; ++kc) {
            const half8 bf = *(const half8*)&Bt[swz64(n, kc * 32 + kg * 8)];
            a = __builtin_amdgcn_mfma_f32_16x16x32_f16(a2[2 + kc], bf, a, 0, 0, 0);
        }
        acc2[nt] = a;
    }
    __builtin_amdgcn_s_setprio(0);

    // ---- + b2, LayerNorm over E (16-lane shfl, v_rsq), store ----
    float s[4] = {0.f, 0.f, 0.f, 0.f}, q[4] = {0.f, 0.f, 0.f, 0.f};
#pragma unroll
    for (int nt = 0; nt < 8; ++nt) {
        const int col = nt * 16 + ln15;
        const float b2v = b2[col];
#pragma unroll
        for (int r2 = 0; r2 < 4; ++r2) {
            const float v = acc2[nt][r2] + b2v;
            acc2[nt][r2] = v;
            s[r2] += v;
            q[r2] += v * v;
        }
    }
#pragma unroll
    for (int m = 1; m < 16; m <<= 1) {
#pragma unroll
        for (int r2 = 0; r2 < 4; ++r2) {
            s[r2] += __shfl_xor(s[r2], m);
            q[r2] += __shfl_xor(q[r2], m);
        }
    }
    const float inv = 1.f / EE;
    float mu[4], rs[4];
#pragma unroll
    for (int r2 = 0; r2 < 4; ++r2) {
        mu[r2] = s[r2] * inv;
        rs[r2] = __builtin_amdgcn_rsqf(fmaxf(q[r2] * inv - mu[r2] * mu[r2], 0.f) + 1e-5f);
    }
#pragma unroll
    for (int nt = 0; nt < 8; ++nt) {
        const int col = nt * 16 + ln15;
        const float g  = gamma[col];
        const float be = beta[col];
#pragma unroll
        for (int r2 = 0; r2 < 4; ++r2) {
            const int rr = w * 16 + kg * 4 + r2;
            out[((size_t)b * NN + n0 + rr) * EE + col] =
                (acc2[nt][r2] - mu[r2]) * rs[r2] * g + be;
        }
    }
}

extern "C" void kernel_launch(void* const* d_in, const int* in_sizes, int n_in,
                              void* d_out, int out_size, void* d_ws, size_t ws_size,
                              hipStream_t stream) {
    const float* pos    = (const float*)d_in[0];
    const float* recip  = (const float*)d_in[1];
    const int*   sgp    = (const int*)d_in[2];
    const float* abc    = (const float*)d_in[3];
    const float* graphs = (const float*)d_in[4];
    const float* wr     = (const float*)d_in[5];
    const float* wi     = (const float*)d_in[6];
    const float* br     = (const float*)d_in[7];
    const float* bi     = (const float*)d_in[8];
    const float* W2     = (const float*)d_in[9];
    const float* b2     = (const float*)d_in[10];
    const float* gm     = (const float*)d_in[11];
    const float* bt     = (const float*)d_in[12];
    float* out = (float*)d_out;

    char* ws = (char*)d_ws;
    _Float16* Mt    = (_Float16*)ws;                                     // 8 MiB
    char* p = ws + (size_t)BB * EE * EE * 2;
    _Float16* W2h   = (_Float16*)p;            p += EE * EE * 2;         // 32 KiB
    float*    bball = (float*)p;               p += (size_t)BB * EE * 4; // 128 KiB
    float*    tabcP = (float*)p;                                         // 256 KiB

    hipLaunchKernelGGL(prep_kernel, dim3(BB), dim3(256), 0, stream,
                       recip, sgp, abc, graphs, wr, wi, br, bi, W2, Mt, bball, tabcP, W2h);
    hipLaunchKernelGGL(main_kernel, dim3(BB * NN / TM), dim3(256), 0, stream,
                       pos, Mt, bball, tabcP, W2h, b2, gm, bt, out);
}